// Round 6
// baseline (453.780 us; speedup 1.0000x reference)
//
#include <hip/hip_runtime.h>

typedef unsigned short u16;
typedef __attribute__((ext_vector_type(8))) short bf16x8;
typedef __attribute__((ext_vector_type(4))) float f32x4;

#define DEV static __device__ __forceinline__

DEV u16 f2bf(float f) {
    unsigned u = __float_as_uint(f);
    u += 0x7FFFu + ((u >> 16) & 1u);
    return (u16)(u >> 16);
}

typedef const __attribute__((address_space(1))) void* gas1_t;
typedef __attribute__((address_space(3))) void* gas3_t;

DEV void gl_lds16(const u16* g, u16* l) {
    __builtin_amdgcn_global_load_lds((gas1_t)g, (gas3_t)l, 16, 0, 0);
}

// swizzled LDS offset (u16 units) for 128B rows of 64 u16, 16B chunks
DEV int sw8(int row, int chunk) { return row * 64 + ((chunk ^ (row & 7)) << 3); }

DEV void ln_body(const float4 v, const float* gam, const float* bet, float* shm,
                 int t, u16* yrow) {
    float s = v.x + v.y + v.z + v.w;
    float ss = v.x * v.x + v.y * v.y + v.z * v.z + v.w * v.w;
#pragma unroll
    for (int o = 1; o < 64; o <<= 1) {
        s += __shfl_xor(s, o);
        ss += __shfl_xor(ss, o);
    }
    float* rs = shm;
    float* rss = shm + 4;
    const int wave = t >> 6, lane = t & 63;
    if (lane == 0) { rs[wave] = s; rss[wave] = ss; }
    __syncthreads();
    const float tot = rs[0] + rs[1] + rs[2] + rs[3];
    const float totss = rss[0] + rss[1] + rss[2] + rss[3];
    const float mu = tot * (1.0f / 1024.0f);
    const float var = totss * (1.0f / 1024.0f) - mu * mu;
    const float rstd = rsqrtf(var + 1e-5f);
    const float4 g4 = ((const float4*)gam)[t];
    const float4 b4 = ((const float4*)bet)[t];
    ushort4 o;
    o.x = f2bf((v.x - mu) * rstd * g4.x + b4.x);
    o.y = f2bf((v.y - mu) * rstd * g4.y + b4.y);
    o.z = f2bf((v.z - mu) * rstd * g4.z + b4.z);
    o.w = f2bf((v.w - mu) * rstd * g4.w + b4.w);
    ((ushort4*)yrow)[t] = o;
}

// ---------------- merged prep ----------------
// [0,4096) LN1 | [4096,7168) qkvW | [7168,8192) oW | [8192,12288) p1W
// | [12288,16384) p2W | [16384,18432) mask pack+transpose | 18432 pbias
__global__ __launch_bounds__(256) void prep_all(const float* __restrict__ Z,
                                                const float* __restrict__ ln1_g,
                                                const float* __restrict__ ln1_b,
                                                const float* __restrict__ qkv_w,
                                                const float* __restrict__ o_w,
                                                const float* __restrict__ p1_w,
                                                const float* __restrict__ p2_w,
                                                const float* __restrict__ qkv_b,
                                                const float* __restrict__ nm,
                                                const float* __restrict__ pm,
                                                u16* __restrict__ Zn,
                                                u16* __restrict__ qkvW,
                                                u16* __restrict__ oW,
                                                u16* __restrict__ p1W,
                                                u16* __restrict__ p2W,
                                                float* __restrict__ pbias,
                                                unsigned* __restrict__ Mpt) {
    __shared__ unsigned T[64 * 65];
    const int bid = blockIdx.x, t = threadIdx.x;
    if (bid < 4096) {            // LN1
        const float4 v = ((const float4*)(Z + (size_t)bid * 1024))[t];
        ln_body(v, ln1_g, ln1_b, (float*)T, t, Zn + (size_t)bid * 1024);
    } else if (bid < 7168) {     // qkv cast + row permute: rows = [V|Q|K], h*64+t
        int i = (bid - 4096) * 256 + t;
        int orow = i >> 8, cc = i & 255;
        int region = orow >> 10, rem = orow & 1023, h = rem >> 6, tt = rem & 63;
        int srow = h * 192 + region * 64 + tt;
        float4 v = ((const float4*)qkv_w)[srow * 256 + cc];
        ushort4 o;
        o.x = f2bf(v.x); o.y = f2bf(v.y); o.z = f2bf(v.z); o.w = f2bf(v.w);
        ((ushort4*)qkvW)[i] = o;
    } else if (bid < 8192) {     // o_w cast
        int i = (bid - 7168) * 256 + t;
        float4 v = ((const float4*)o_w)[i];
        ushort4 o;
        o.x = f2bf(v.x); o.y = f2bf(v.y); o.z = f2bf(v.z); o.w = f2bf(v.w);
        ((ushort4*)oW)[i] = o;
    } else if (bid < 12288) {    // p1_w cast
        int i = (bid - 8192) * 256 + t;
        float4 v = ((const float4*)p1_w)[i];
        ushort4 o;
        o.x = f2bf(v.x); o.y = f2bf(v.y); o.z = f2bf(v.z); o.w = f2bf(v.w);
        ((ushort4*)p1W)[i] = o;
    } else if (bid < 16384) {    // p2_w cast
        int i = (bid - 12288) * 256 + t;
        float4 v = ((const float4*)p2_w)[i];
        ushort4 o;
        o.x = f2bf(v.x); o.y = f2bf(v.y); o.z = f2bf(v.z); o.w = f2bf(v.w);
        ((ushort4*)p2W)[i] = o;
    } else if (bid < 18432) {    // mask pack + transpose -> Mpt[b][m][q]
        int bid2 = bid - 16384;           // b(2) x qt(32) x mt(32)
        int b = bid2 >> 10, rem = bid2 & 1023, qt = rem >> 5, mt = rem & 31;
        const size_t base = (size_t)b * 2048 * 2048;
        const int tq = t >> 4, tm4 = (t & 15) * 4;
#pragma unroll
        for (int s = 0; s < 4; s++) {
            const int q = qt * 64 + s * 16 + tq;
            const size_t off = base + (size_t)q * 2048 + mt * 64 + tm4;
            const float4 a = *(const float4*)(nm + off);
            const float4 p = *(const float4*)(pm + off);
            unsigned* row = T + (s * 16 + tq);    // T[m][q], stride 65
            row[(tm4 + 0) * 65] = ((unsigned)f2bf(p.x) << 16) | f2bf(a.x * 1.4426950f);
            row[(tm4 + 1) * 65] = ((unsigned)f2bf(p.y) << 16) | f2bf(a.y * 1.4426950f);
            row[(tm4 + 2) * 65] = ((unsigned)f2bf(p.z) << 16) | f2bf(a.z * 1.4426950f);
            row[(tm4 + 3) * 65] = ((unsigned)f2bf(p.w) << 16) | f2bf(a.w * 1.4426950f);
        }
        __syncthreads();
#pragma unroll
        for (int s = 0; s < 4; s++) {
            const int ml = s * 16 + tq;
            uint4 o;
            o.x = T[ml * 65 + tm4 + 0];
            o.y = T[ml * 65 + tm4 + 1];
            o.z = T[ml * 65 + tm4 + 2];
            o.w = T[ml * 65 + tm4 + 3];
            *(uint4*)(Mpt + base + (size_t)(mt * 64 + ml) * 2048 + qt * 64 + tm4) = o;
        }
    } else {                     // qkv bias permute (3072 elements)
#pragma unroll
        for (int k = 0; k < 12; k++) {
            int i = k * 256 + t;
            int region = i >> 10, rem = i & 1023, h = rem >> 6, tt = rem & 63;
            pbias[i] = qkv_b[h * 192 + region * 64 + tt];
        }
    }
}

// ---------------- LayerNorm (D=1024) f32 -> bf16 ----------------
__global__ __launch_bounds__(256) void ln_bf16(const float* __restrict__ x,
                                               const float* __restrict__ gam,
                                               const float* __restrict__ bet,
                                               u16* __restrict__ y) {
    __shared__ float shm[8];
    const int row = blockIdx.x, t = threadIdx.x;
    const float4 v = ((const float4*)(x + (size_t)row * 1024))[t];
    ln_body(v, gam, bet, shm, t, y + (size_t)row * 1024);
}

// ---- final combine: out = p0 + p1 + bias + Z1 ----
__global__ __launch_bounds__(256) void out_comb(const float* __restrict__ p0,
                                                const float* __restrict__ p1,
                                                const float* __restrict__ bias,
                                                const float* __restrict__ Z1,
                                                float* __restrict__ out) {
    int i = blockIdx.x * 256 + threadIdx.x;   // 1048576 float4s
    float4 a = ((const float4*)p0)[i];
    float4 c = ((const float4*)p1)[i];
    float4 z = ((const float4*)Z1)[i];
    float4 b = ((const float4*)bias)[i & 255];
    float4 o;
    o.x = a.x + c.x + z.x + b.x; o.y = a.y + c.y + z.y + b.y;
    o.z = a.z + c.z + z.z + b.z; o.w = a.w + c.w + z.w + b.w;
    ((float4*)out)[i] = o;
}

// ---------------- GEMM: C[M,N] = A[M,K-slice] @ Bt[N,K-slice]^T ----------------
// BN=128: waves 2x2, acc 4x4. BN=64: waves 4x1, acc 2x4.
// EPI 0: +pbias; region: 0 -> bf16 Vsc(out0), 1 -> Q bf16(out1), 2 -> K bf16(out2)
// EPI 1: +res, write f32 out0 (o-proj -> Z1)
// EPI 2: +bias, relu, write bf16 out0
// EPI 4: raw f32 partial -> out0 + z*M*N
template <int EPI, int BN>
__global__ __launch_bounds__(256, 3) void gemm_bt(const u16* __restrict__ A,
                                                  const u16* __restrict__ Bt,
                                                  const float* __restrict__ bias,
                                                  const float* __restrict__ res,
                                                  void* __restrict__ out0,
                                                  void* __restrict__ out1,
                                                  void* __restrict__ out2,
                                                  int M, int N, int K, int ldk) {
    constexpr int RT = (BN == 128) ? 4 : 2;
    __shared__ __align__(16) u16 As[128 * 32];
    __shared__ __align__(16) u16 Bs[BN * 32];
    const int tid = threadIdx.x;
    const int wave = tid >> 6, lane = tid & 63;
    const int lhi = lane >> 4, llo = lane & 15;
    const int bx = blockIdx.x, by = blockIdx.y;
    const int kz = blockIdx.z * K;
    const int wr = (BN == 128) ? (wave >> 1) : wave;
    const int wc = (BN == 128) ? (wave & 1) : 0;

    const int arow = wave * 32 + (lane >> 2);
    const int acol = (lane & 3) * 8;
    const u16* gA = A + (size_t)(by * 128 + arow) * ldk + kz + acol;
    u16* lA = As + wave * 1024 + lane * 8;
    const int brow = (BN == 128) ? arow : (wave * 16 + (lane >> 2));
    const u16* gB = Bt + (size_t)(bx * BN + brow) * ldk + kz + acol;
    u16* lB = Bs + ((BN == 128) ? wave * 1024 : wave * 512) + lane * 8;

    const f32x4 zero = {0.f, 0.f, 0.f, 0.f};
    f32x4 acc[RT][4];
#pragma unroll
    for (int i = 0; i < RT; i++)
#pragma unroll
        for (int j = 0; j < 4; j++) acc[i][j] = zero;

    for (int k0 = 0; k0 < K; k0 += 32) {
        __syncthreads();
        gl_lds16(gA, lA);
        gl_lds16(gA + 16 * (size_t)ldk, lA + 512);
        gl_lds16(gB, lB);
        if (BN == 128) gl_lds16(gB + 16 * (size_t)ldk, lB + 512);
        gA += 32; gB += 32;
        __syncthreads();
        bf16x8 af[RT], bfr[4];
#pragma unroll
        for (int i = 0; i < RT; i++)
            af[i] = *(const bf16x8*)(As + (wr * (RT * 16) + i * 16 + llo) * 32 + lhi * 8);
#pragma unroll
        for (int j = 0; j < 4; j++)
            bfr[j] = *(const bf16x8*)(Bs + (wc * 64 + j * 16 + llo) * 32 + lhi * 8);
#pragma unroll
        for (int i = 0; i < RT; i++)
#pragma unroll
            for (int j = 0; j < 4; j++)
                acc[i][j] = __builtin_amdgcn_mfma_f32_16x16x32_bf16(af[i], bfr[j], acc[i][j], 0, 0, 0);
    }

    const int rbase = by * 128 + wr * (RT * 16) + lhi * 4;
    const int cbase = bx * BN + wc * 64 + llo;
    float* pout = (EPI == 4) ? ((float*)out0 + (size_t)blockIdx.z * M * N) : (float*)out0;
#pragma unroll
    for (int i = 0; i < RT; i++) {
#pragma unroll
        for (int j = 0; j < 4; j++) {
#pragma unroll
            for (int r = 0; r < 4; r++) {
                const int row = rbase + i * 16 + r;
                const int col = cbase + j * 16;
                float v = acc[i][j][r];
                if constexpr (EPI == 0) {
                    v += bias[col];
                    const int region = col >> 10;   // uniform per block
                    const int c = col & 1023;       // h*64 + t
                    const int b = row >> 11, n = row & 2047;
                    if (region == 0) {
                        ((u16*)out0)[(size_t)row * 1024 + c] = f2bf(v);  // Vsc bf16
                    } else {
                        const int h = c >> 6, tt = c & 63;
                        u16* dst = (region == 1) ? (u16*)out1 : (u16*)out2;
                        dst[(((size_t)(b * 16 + h)) * 2048 + n) * 64 + tt] = f2bf(v);
                    }
                } else if constexpr (EPI == 1) {
                    ((float*)out0)[(size_t)row * N + col] = v + res[(size_t)row * N + col];
                } else if constexpr (EPI == 2) {
                    v += bias[col];
                    v = v > 0.f ? v : 0.f;
                    ((u16*)out0)[(size_t)row * N + col] = f2bf(v);
                } else {
                    pout[(size_t)row * N + col] = v;
                }
            }
        }
    }
}

// ---------------- V transpose: Vsc bf16 [B*N][1024] -> Vt bf16 [BH][64][2048] --
__global__ __launch_bounds__(256) void vtrans(const u16* __restrict__ Vsc,
                                              u16* __restrict__ Vt) {
    __shared__ u16 Ts[64 * 72];
    const int nt = blockIdx.x;  // n-tile (0..31)
    const int bh = blockIdx.y;  // 0..31
    const int b = bh >> 4, h = bh & 15;
    const int t = threadIdx.x;
    const int n0 = nt * 64;
    const int nr = t >> 2;
    const int dq = (t & 3) * 16;
    const u16* src = Vsc + ((size_t)(b * 2048 + n0 + nr)) * 1024 + h * 64 + dq;
    bf16x8 a0 = *(const bf16x8*)src;
    bf16x8 a1 = *(const bf16x8*)(src + 8);
    u16* c0 = Ts + nr;
#pragma unroll
    for (int k = 0; k < 8; k++) c0[(dq + k) * 72] = (u16)a0[k];
#pragma unroll
    for (int k = 0; k < 8; k++) c0[(dq + 8 + k) * 72] = (u16)a1[k];
    __syncthreads();
    const int d = t >> 2, n8 = (t & 3) * 16;
    bf16x8 o0 = *(const bf16x8*)(Ts + d * 72 + n8);
    bf16x8 o1 = *(const bf16x8*)(Ts + d * 72 + n8 + 8);
    u16* dst = Vt + ((size_t)bh * 64 + d) * 2048 + n0 + n8;
    *(bf16x8*)dst = o0;
    *(bf16x8*)(dst + 8) = o1;
}

// ---------------- fused flash-style attention v5 ----------------
// grid 1024, id = hh*64 + b*32 + qt. q-tile 64, m-tile 64, 4 blocks/CU.
// Masks pre-transposed: Mpt[b][m][q] -> 4 dwordx4 loads per lane per iter.
__global__ __launch_bounds__(256, 4) void attn_fused5(const u16* __restrict__ Qg,
                                                      const u16* __restrict__ Kg,
                                                      const u16* __restrict__ Vt,
                                                      const unsigned* __restrict__ Mpt,
                                                      u16* __restrict__ attnL) {
    __shared__ __align__(16) u16 Qs[64 * 64];
    __shared__ __align__(16) u16 Ks[64 * 64];
    __shared__ __align__(16) u16 Vs[64 * 64];   // [d][m]
    __shared__ __align__(16) u16 Ps[64 * 72];   // padded rows
    const int tid = threadIdx.x, wave = tid >> 6, lane = tid & 63;
    const int lhi = lane >> 4, llo = lane & 15;
    const int id = blockIdx.x;
    const int hh = id >> 6, rem = id & 63;
    const int b = rem >> 5, qt = rem & 31;
    const int bh = b * 16 + hh;
    const int q0 = qt * 64;
    const int l3 = lane >> 3, l7 = lane & 7;
    const int swcol = (l7 ^ (l3 & 7)) * 8;   // swizzled source column (u16)

    // stage Q tile (64 rows) once
#pragma unroll
    for (int s = 0; s < 2; s++) {
        const int row = wave * 16 + s * 8 + l3;
        gl_lds16(Qg + ((size_t)bh * 2048 + q0 + row) * 64 + swcol,
                 Qs + wave * 1024 + s * 512 + lane * 8);
    }

    const unsigned* Mb = Mpt + (size_t)b * 2048 * 2048 + (size_t)llo * 2048 +
                         (q0 + wave * 16 + lhi * 4);

    const f32x4 zero = {0.f, 0.f, 0.f, 0.f};
    f32x4 accO[4];
    float lsum[4];
#pragma unroll
    for (int j = 0; j < 4; j++) accO[j] = zero;
#pragma unroll
    for (int r = 0; r < 4; r++) lsum[r] = 0.f;

    const float CS = 0.125f * 1.4426950f;
    const int pb0 = (wave * 16 + lhi * 4) * 72 + llo;

    for (int m0 = 0; m0 < 2048; m0 += 64) {
        __syncthreads();
        // stage K[m0..m0+64) and Vt[:, m0..m0+64) (swizzled)
#pragma unroll
        for (int s = 0; s < 2; s++) {
            const int row = wave * 16 + s * 8 + l3;
            gl_lds16(Kg + ((size_t)bh * 2048 + m0 + row) * 64 + swcol,
                     Ks + wave * 1024 + s * 512 + lane * 8);
            gl_lds16(Vt + ((size_t)bh * 64 + row) * 2048 + m0 + swcol,
                     Vs + wave * 1024 + s * 512 + lane * 8);
        }
        // 4 dwordx4 mask loads ride the staging latency window
        uint4 mv[4];
#pragma unroll
        for (int j = 0; j < 4; j++)
            mv[j] = *(const uint4*)(Mb + (size_t)(m0 + j * 16) * 2048);
        __syncthreads();

        // S = Q K^T  (wave's 16 q-rows x 64 m-cols)
        f32x4 sacc[4];
#pragma unroll
        for (int j = 0; j < 4; j++) sacc[j] = zero;
#pragma unroll
        for (int kk = 0; kk < 2; kk++) {
            const bf16x8 aq = *(const bf16x8*)(Qs + sw8(wave * 16 + llo, kk * 4 + lhi));
#pragma unroll
            for (int j = 0; j < 4; j++) {
                const bf16x8 bk = *(const bf16x8*)(Ks + sw8(j * 16 + llo, kk * 4 + lhi));
                sacc[j] = __builtin_amdgcn_mfma_f32_16x16x32_bf16(aq, bk, sacc[j], 0, 0, 0);
            }
        }

        // P = exp2(S*CS + nm) * pm ; l += exp (unmasked denominator)
#pragma unroll
        for (int j = 0; j < 4; j++) {
            const unsigned* mj = (const unsigned*)&mv[j];
#pragma unroll
            for (int r = 0; r < 4; r++) {
                const unsigned u = mj[r];
                const float nm = __uint_as_float(u << 16);
                const float pm = __uint_as_float(u & 0xFFFF0000u);
                const float e = __builtin_amdgcn_exp2f(fmaf(sacc[j][r], CS, nm));
                lsum[r] += e;
                const float p = e * pm;
                Ps[pb0 + r * 72 + j * 16] = (u16)(__float_as_uint(p) >> 16);
            }
        }

        // O += P @ V  (Ps rows wave-private)
#pragma unroll
        for (int kk = 0; kk < 2; kk++) {
            const bf16x8 ap = *(const bf16x8*)(Ps + (wave * 16 + llo) * 72 + kk * 32 + lhi * 8);
#pragma unroll
            for (int jd = 0; jd < 4; jd++) {
                const bf16x8 bv = *(const bf16x8*)(Vs + sw8(jd * 16 + llo, kk * 4 + lhi));
                accO[jd] = __builtin_amdgcn_mfma_f32_16x16x32_bf16(ap, bv, accO[jd], 0, 0, 0);
            }
        }
    }

    // reduce l over the 16 llo-lanes, epilogue leaky_relu(O/l)
#pragma unroll
    for (int r = 0; r < 4; r++) {
#pragma unroll
        for (int o = 1; o < 16; o <<= 1) lsum[r] += __shfl_xor(lsum[r], o);
        lsum[r] = 1.0f / lsum[r];
    }
#pragma unroll
    for (int jd = 0; jd < 4; jd++)
#pragma unroll
        for (int r = 0; r < 4; r++) {
            float v = accO[jd][r] * lsum[r];
            v = v >= 0.f ? v : 0.01f * v;
            const int q = q0 + wave * 16 + lhi * 4 + r;
            attnL[((size_t)b * 2048 + q) * 1024 + hh * 64 + jd * 16 + llo] = f2bf(v);
        }
}

// ---------------- launcher ----------------
extern "C" void kernel_launch(void* const* d_in, const int* in_sizes, int n_in,
                              void* d_out, int out_size, void* d_ws, size_t ws_size,
                              hipStream_t stream) {
    const float* Z     = (const float*)d_in[0];
    const float* nmask = (const float*)d_in[1];
    const float* pmask = (const float*)d_in[2];
    const float* ln1_g = (const float*)d_in[3];
    const float* ln1_b = (const float*)d_in[4];
    const float* qkv_w = (const float*)d_in[5];
    const float* qkv_b = (const float*)d_in[6];
    const float* o_w   = (const float*)d_in[7];
    const float* ln2_g = (const float*)d_in[8];
    const float* ln2_b = (const float*)d_in[9];
    const float* p1_w  = (const float*)d_in[10];
    const float* p1_b  = (const float*)d_in[11];
    const float* p2_w  = (const float*)d_in[12];
    const float* p2_b  = (const float*)d_in[13];
    float* out = (float*)d_out;

    char* w = (char*)d_ws;
    auto take = [&](size_t bytes) -> char* {
        char* p = w;
        w += (bytes + 255) & ~(size_t)255;
        return p;
    };
    u16* qkvW   = (u16*)take((size_t)3072 * 1024 * 2);
    u16* oW     = (u16*)take((size_t)1024 * 1024 * 2);
    u16* p1W    = (u16*)take((size_t)4096 * 1024 * 2);
    u16* p2W    = (u16*)take((size_t)1024 * 4096 * 2);
    u16* Zn     = (u16*)take((size_t)4096 * 1024 * 2);   // reused for Zn2
    u16* Qb     = (u16*)take((size_t)32 * 2048 * 64 * 2);
    u16* Kb     = (u16*)take((size_t)32 * 2048 * 64 * 2);
    u16* Vt     = (u16*)take((size_t)32 * 64 * 2048 * 2);
    u16* attnL  = (u16*)take((size_t)4096 * 1024 * 2);
    float* Z1   = (float*)take((size_t)4096 * 1024 * 4);
    u16* hbuf   = (u16*)take((size_t)4096 * 4096 * 2);   // 33.55 MB
    unsigned* Mpt = (unsigned*)take((size_t)2 * 2048 * 2048 * 4);  // 33.55 MB
    float* pbias = (float*)take((size_t)3072 * 4);
    u16* Vsc      = (u16*)hbuf;            // alias: dead before hbuf written
    float* part01 = (float*)Mpt;           // alias: Mpt dead after attention

    // merged prep: LN1 + weight casts + mask pack/transpose + bias permute
    prep_all<<<dim3(18433), 256, 0, stream>>>(Z, ln1_g, ln1_b, qkv_w, o_w, p1_w, p2_w,
                                              qkv_b, nmask, pmask,
                                              Zn, qkvW, oW, p1W, p2W, pbias, Mpt);
    // QKV projection: V -> bf16 scratch, Q/K -> bf16 [BH][N][64]
    gemm_bt<0, 128><<<dim3(24, 32), 256, 0, stream>>>(Zn, qkvW, pbias, nullptr,
                                                      Vsc, Qb, Kb, 4096, 3072, 1024, 1024);
    // V transpose -> Vt [BH][64][2048]
    vtrans<<<dim3(32, 32), 256, 0, stream>>>(Vsc, Vt);
    // attention (4 blocks/CU)
    attn_fused5<<<dim3(1024), 256, 0, stream>>>(Qb, Kb, Vt, Mpt, attnL);
    // o-projection + residual -> Z1 f32  (BN=64, grid 512)
    gemm_bt<1, 64><<<dim3(16, 32), 256, 0, stream>>>(attnL, oW, nullptr, Z,
                                                     Z1, nullptr, nullptr, 4096, 1024, 1024, 1024);
    // LN2
    ln_bf16<<<dim3(4096), 256, 0, stream>>>(Z1, ln2_g, ln2_b, Zn);
    // MLP up + relu -> hbuf (bf16)
    gemm_bt<2, 128><<<dim3(32, 32), 256, 0, stream>>>(Zn, p1W, p1_b, nullptr,
                                                      hbuf, nullptr, nullptr, 4096, 4096, 1024, 1024);
    // MLP down, split-K=2 -> f32 partials in Mpt region
    gemm_bt<4, 128><<<dim3(8, 32, 2), 256, 0, stream>>>(hbuf, p2W, nullptr, nullptr,
                                                        part01, nullptr, nullptr, 4096, 1024, 2048, 4096);
    // final combine -> out
    out_comb<<<dim3(4096), 256, 0, stream>>>(part01, part01 + (size_t)4096 * 1024, p2_b, Z1, out);
}